// Round 8
// baseline (488.305 us; speedup 1.0000x reference)
//
#include <hip/hip_runtime.h>

typedef unsigned short u16;
typedef __attribute__((ext_vector_type(8))) short short8;   // 8 bf16
typedef __attribute__((ext_vector_type(4))) float f32x4;

// B=256, N=H=512, C=A=64, L=3, FC=256, FFC=32.  M := B*C = 16384 rows of xm.
// Master state is bf16 (residual re-read in bf16); fp32 only where the tail needs it.

__device__ __forceinline__ u16 f2b(float f) {
    union { float f; unsigned int i; } v; v.f = f;
    unsigned int x = v.i;
    x += 0x7fffu + ((x >> 16) & 1u);   // RNE
    return (u16)(x >> 16);
}
__device__ __forceinline__ float b2f(u16 u) {
    union { unsigned int i; float f; } v;
    v.i = ((unsigned int)u) << 16;
    return v.f;
}
// async global->LDS, 16B per lane; LDS dest = wave-uniform base + lane*16
__device__ __forceinline__ void gl_lds16(const u16* g, u16* l) {
    __builtin_amdgcn_global_load_lds((__attribute__((address_space(1))) void*)(u16*)g,
                                     (__attribute__((address_space(3))) void*)l, 16, 0, 0);
}

// ---------------- fp32 -> bf16 weight conversion
__global__ __launch_bounds__(256) void k_cvt(const float* __restrict__ src, u16* __restrict__ dst, int n4) {
    int i = blockIdx.x * 256 + threadIdx.x;
    if (i < n4) {
        float4 v = ((const float4*)src)[i];
        ushort4 o; o.x = f2b(v.x); o.y = f2b(v.y); o.z = f2b(v.z); o.w = f2b(v.w);
        ((ushort4*)dst)[i] = o;
    }
}

// ---------------- transpose: x[b,n,c] -> xmb[(b*64+c)*512+n] bf16
__global__ __launch_bounds__(256) void k_transpose(const float* __restrict__ x, u16* __restrict__ xmb) {
    __shared__ float tile[64][65];
    const int b  = blockIdx.y;
    const int n0 = blockIdx.x * 64;
    const int t  = threadIdx.x;
    const int c  = t & 63;
    const int dn = t >> 6;
#pragma unroll
    for (int i = 0; i < 16; ++i) {
        int nl = dn + i * 4;
        tile[c][nl] = x[((size_t)b * 512 + n0 + nl) * 64 + c];
    }
    __syncthreads();
    const int nl = t & 63;
    const int cb = (t >> 6) * 16;
#pragma unroll
    for (int i = 0; i < 16; ++i) {
        int c2 = cb + i;
        xmb[((size_t)b * 64 + c2) * 512 + n0 + nl] = f2b(tile[c2][nl]);
    }
}

// ---------------- proj[b,a]
__global__ __launch_bounds__(64) void k_proj(const float* __restrict__ occ, const float* __restrict__ pw,
                                             const float* __restrict__ pb, float* __restrict__ proj) {
    const int b = blockIdx.x;
    const int a = threadIdx.x;
    const float* ob = occ + (size_t)b * 512;
    const float* wr = pw + (size_t)a * 512;
    float acc = 0.f;
    for (int n = 0; n < 512; ++n) acc += ob[n] * wr[n];
    proj[b * 64 + a] = acc + pb[a];
}

// ---------------- fused gates + P: per row r=(b,c): m1,m2 from bf16 xm, then softmax P1,P2
__global__ __launch_bounds__(64) void k_pm(const u16* __restrict__ xmb,
                                           const float* __restrict__ g1w, const float* __restrict__ g1b,
                                           const float* __restrict__ g2w, const float* __restrict__ g2b,
                                           const float* __restrict__ proj, float* __restrict__ vb) {
    const int r = blockIdx.x;
    const int b = r >> 6, c = r & 63;
    const int lane = threadIdx.x;
    const u16* row = xmb + (size_t)r * 512 + lane * 8;
    uint4 xv = *(const uint4*)row;
    const u16* xp = (const u16*)&xv;
    float4 w1a = *(const float4*)(g1w + lane * 8);
    float4 w1b = *(const float4*)(g1w + lane * 8 + 4);
    float4 w2a = *(const float4*)(g2w + lane * 8);
    float4 w2b = *(const float4*)(g2w + lane * 8 + 4);
    float g1v[8] = {w1a.x, w1a.y, w1a.z, w1a.w, w1b.x, w1b.y, w1b.z, w1b.w};
    float g2v[8] = {w2a.x, w2a.y, w2a.z, w2a.w, w2b.x, w2b.y, w2b.z, w2b.w};
    float a1 = 0.f, a2 = 0.f;
#pragma unroll
    for (int e = 0; e < 8; ++e) {
        float xvf = b2f(xp[e]);
        a1 += xvf * g1v[e];
        a2 += xvf * g2v[e];
    }
    a1 += proj[b * 64 + lane] * g1w[512 + lane];   // AATE part
    a2 += proj[b * 64 + c]    * g2w[512 + lane];   // AATE_T part
    for (int off = 32; off; off >>= 1) { a1 += __shfl_xor(a1, off); a2 += __shfl_xor(a2, off); }
    float m1 = tanhf(a1 + g1b[0]); m1 = m1 > 0.f ? m1 : 0.f;
    float m2 = tanhf(a2 + g2b[0]); m2 = m2 > 0.f ? m2 : 0.f;
    const int a = lane;
    float s1 = m1 * vb[(size_t)r * 128 + a];       s1 = s1 > 0.f ? s1 : 0.f;
    float s2 = m2 * vb[(size_t)r * 128 + 64 + a];  s2 = s2 > 0.f ? s2 : 0.f;
    float mx1 = s1, mx2 = s2;
    for (int off = 32; off; off >>= 1) { mx1 = fmaxf(mx1, __shfl_xor(mx1, off)); mx2 = fmaxf(mx2, __shfl_xor(mx2, off)); }
    float e1 = expf(s1 - mx1), e2 = expf(s2 - mx2);
    float su1 = e1, su2 = e2;
    for (int off = 32; off; off >>= 1) { su1 += __shfl_xor(su1, off); su2 += __shfl_xor(su2, off); }
    vb[(size_t)r * 128 + a]      = proj[b * 64 + a] + e1 / su1;
    vb[(size_t)r * 128 + 64 + a] = proj[b * 64 + c] + e2 / su2;
}

// ---------------- adp -> transposed bf16: adpT[(b*64+v)*64 + c] = adp[c][v]
__global__ __launch_bounds__(256) void k_adp(const float* __restrict__ vb, u16* __restrict__ adpT) {
    __shared__ float P1s[64][64];
    __shared__ float P2s[64][65];
    __shared__ __align__(16) u16 Tl[64 * 72];
    const int b = blockIdx.x;
    const int t = threadIdx.x;
#pragma unroll
    for (int i = 0; i < 16; ++i) {
        int idx = t + 256 * i;
        int c = idx >> 6, a = idx & 63;
        P1s[c][a] = vb[((size_t)b * 64 + c) * 128 + a];
        P2s[c][a] = vb[((size_t)b * 64 + c) * 128 + 64 + a];
    }
    __syncthreads();
    const int lane = t & 63;   // v (softmax dim)
    const int w = t >> 6;
    for (int ci = 0; ci < 16; ++ci) {
        int c = w + ci * 4;
        float s = 0.f;
        for (int a = 0; a < 64; ++a) s += P1s[c][a] * P2s[lane][a];
        s = fmaxf(s, 0.f);
        float mx = s;
        for (int off = 32; off; off >>= 1) mx = fmaxf(mx, __shfl_xor(mx, off));
        float e = expf(s - mx);
        float su = e;
        for (int off = 32; off; off >>= 1) su += __shfl_xor(su, off);
        Tl[lane * 72 + c] = f2b(e / su);     // transposed: row v, col c
    }
    __syncthreads();
    const int v = t >> 2, ck = (t & 3) * 16;
    u16* dst = adpT + ((size_t)b * 64 + v) * 64 + ck;
    *(uint4*)dst       = *(const uint4*)&Tl[v * 72 + ck];
    *(uint4*)(dst + 8) = *(const uint4*)&Tl[v * 72 + ck + 8];
}

// ---------------- fused double nconv via MFMA: x1 = adp^T X, x2 = adp^T x1 (per b, n-tile 128)
__global__ __launch_bounds__(256) void k_nconv2(const u16* __restrict__ Xbf, const u16* __restrict__ adpT,
                                                u16* __restrict__ x1bf, u16* __restrict__ x2bf) {
    __shared__ __align__(16) u16 Ts[64 * 72];    // adpT rows v, cols c (k)
    __shared__ __align__(16) u16 Xs[128 * 72];   // XT rows n-local, cols c; reused for x1T
    const int b  = blockIdx.y;
    const int n0 = blockIdx.x * 128;
    const int t  = threadIdx.x;
    const int lane = t & 63, w = t >> 6;
    const int lrow = lane & 15, q = lane >> 4;
    const int wn = w * 32;

    { // stage adpT (already transposed, coalesced)
        int v = t >> 2, ck = (t & 3) * 8;
        const u16* src = adpT + ((size_t)b * 64 + v) * 64;
        *(uint4*)&Ts[v * 72 + ck]      = *(const uint4*)(src + ck);
        *(uint4*)&Ts[v * 72 + ck + 32] = *(const uint4*)(src + ck + 32);
    }
    { // stage X with in-LDS transpose: Xs[n][c]
        int c = t >> 2;
        const u16* xr = Xbf + ((size_t)b * 64 + c) * 512 + n0;
#pragma unroll
        for (int j = 0; j < 4; ++j) {
            int nn = j * 32 + (t & 3) * 8;
            uint4 vv = *(const uint4*)(xr + nn);
            const u16* pv = (const u16*)&vv;
#pragma unroll
            for (int e = 0; e < 8; ++e) Xs[(nn + e) * 72 + c] = pv[e];
        }
    }
    __syncthreads();

    const f32x4 zero = {0.f, 0.f, 0.f, 0.f};
    f32x4 acc[4][2];
#pragma unroll
    for (int mt = 0; mt < 4; ++mt)
#pragma unroll
        for (int nt = 0; nt < 2; ++nt) acc[mt][nt] = zero;

#pragma unroll
    for (int ks = 0; ks < 2; ++ks) {
        short8 af[4], bfr[2];
#pragma unroll
        for (int mt = 0; mt < 4; ++mt) af[mt]  = *(const short8*)&Ts[(mt * 16 + lrow) * 72 + ks * 32 + q * 8];
#pragma unroll
        for (int nt = 0; nt < 2; ++nt) bfr[nt] = *(const short8*)&Xs[(wn + nt * 16 + lrow) * 72 + ks * 32 + q * 8];
#pragma unroll
        for (int mt = 0; mt < 4; ++mt)
#pragma unroll
            for (int nt = 0; nt < 2; ++nt)
                acc[mt][nt] = __builtin_amdgcn_mfma_f32_16x16x32_bf16(af[mt], bfr[nt], acc[mt][nt], 0, 0, 0);
    }
    __syncthreads();   // all Xs reads done

    // write x1 -> global and x1^T -> Xs (for round 2)
#pragma unroll
    for (int mt = 0; mt < 4; ++mt)
#pragma unroll
        for (int nt = 0; nt < 2; ++nt) {
            int nl = wn + nt * 16 + lrow;
            ushort4 u;
            u.x = f2b(acc[mt][nt][0]); u.y = f2b(acc[mt][nt][1]);
            u.z = f2b(acc[mt][nt][2]); u.w = f2b(acc[mt][nt][3]);
            *(ushort4*)&Xs[nl * 72 + mt * 16 + q * 4] = u;
#pragma unroll
            for (int i = 0; i < 4; ++i)
                x1bf[((size_t)(b * 64 + mt * 16 + q * 4 + i)) * 512 + n0 + nl] = ((const u16*)&u)[i];
        }
    __syncthreads();

    f32x4 acc2[4][2];
#pragma unroll
    for (int mt = 0; mt < 4; ++mt)
#pragma unroll
        for (int nt = 0; nt < 2; ++nt) acc2[mt][nt] = zero;
#pragma unroll
    for (int ks = 0; ks < 2; ++ks) {
        short8 af[4], bfr[2];
#pragma unroll
        for (int mt = 0; mt < 4; ++mt) af[mt]  = *(const short8*)&Ts[(mt * 16 + lrow) * 72 + ks * 32 + q * 8];
#pragma unroll
        for (int nt = 0; nt < 2; ++nt) bfr[nt] = *(const short8*)&Xs[(wn + nt * 16 + lrow) * 72 + ks * 32 + q * 8];
#pragma unroll
        for (int mt = 0; mt < 4; ++mt)
#pragma unroll
            for (int nt = 0; nt < 2; ++nt)
                acc2[mt][nt] = __builtin_amdgcn_mfma_f32_16x16x32_bf16(af[mt], bfr[nt], acc2[mt][nt], 0, 0, 0);
    }
#pragma unroll
    for (int mt = 0; mt < 4; ++mt)
#pragma unroll
        for (int nt = 0; nt < 2; ++nt) {
            int nl = wn + nt * 16 + lrow;
#pragma unroll
            for (int i = 0; i < 4; ++i)
                x2bf[((size_t)(b * 64 + mt * 16 + q * 4 + i)) * 512 + n0 + nl] = f2b(acc2[mt][nt][i]);
        }
}

// ---------------- MFMA GEMM, BK=64 double-buffered global_load_lds, swizzled 64B-row LDS layout.
// Each buffer holds two BK=32 chunks (proven layout reused). One barrier per 64-k iter:
// barrier -> DMA(next 2 chunks)->other buf -> compute 2 chunks. Residual read in bf16.
template<int BM, int BN>
__global__ __launch_bounds__(256) void mfma_gemm(
    const u16* __restrict__ A0, const u16* __restrict__ A1, const u16* __restrict__ A2,
    const u16* __restrict__ W0, const u16* __restrict__ W1, int nsplit,
    const float* __restrict__ bias0, const float* __restrict__ bias1,
    const u16* __restrict__ resbf, float* __restrict__ out, u16* __restrict__ outbf,
    int N, int K, int relu)
{
    constexpr int MT = BM / 32;       // m-tiles of 16 per wave (wave tile BM/2 x BN/2)
    constexpr int NT = BN / 32;
    constexpr int AI = BM / 16;       // A DMA wave-instrs per 32-k chunk (across 4 waves)
    constexpr int BI = BN / 16;
    constexpr int CH = (BM + BN) * 32;   // one 32-k chunk (A|B)
    __shared__ __align__(16) u16 SM[4 * CH];   // 2 buffers x 2 chunks
    const int t    = threadIdx.x;
    const int m0   = blockIdx.x * BM;
    const int n0   = blockIdx.y * BN;
    const int lane = t & 63;
    const int w    = t >> 6;
    const int wm   = (w >> 1) * (BM / 2);
    const int wn   = (w & 1) * (BN / 2);
    const int lrow = lane & 15;
    const int q    = lane >> 4;
    const int sr16 = lane >> 2;       // row within 16-row DMA group
    const int sp   = lane & 3;        // 16B pos within 64B row

    // stage one 32-k chunk into slot (buf,ch)
    auto stage32 = [&](int k0, int buf, int ch) {
        u16* As = SM + (buf * 2 + ch) * CH;
        u16* Bs = As + BM * 32;
        const u16* Abase = A0;
        int kloc = k0;
        if (K > 512) {
            int seg = k0 >> 9;
            Abase = (seg == 0) ? A0 : ((seg == 1) ? A1 : A2);
            kloc = k0 & 511;
        }
#pragma unroll
        for (int jj = 0; jj < AI / 4; ++jj) {
            int j = jj * 4 + w;
            int row = j * 16 + sr16;
            int c = (sp - (row >> 1)) & 3;
            gl_lds16(Abase + (size_t)(m0 + row) * 512 + kloc + c * 8, As + j * 512);
        }
#pragma unroll
        for (int jj = 0; jj < BI / 4; ++jj) {
            int j = jj * 4 + w;
            int row = j * 16 + sr16;
            int n = n0 + row;
            const u16* wr = (n < nsplit) ? (W0 + (size_t)n * K) : (W1 + (size_t)(n - nsplit) * K);
            int c = (sp - (row >> 1)) & 3;
            gl_lds16(wr + k0 + c * 8, Bs + j * 512);
        }
    };

    const f32x4 zero = {0.f, 0.f, 0.f, 0.f};
    f32x4 acc[MT][NT];
#pragma unroll
    for (int i = 0; i < MT; ++i)
#pragma unroll
        for (int j = 0; j < NT; ++j) acc[i][j] = zero;

    stage32(0, 0, 0);
    stage32(32, 0, 1);
    const int iters = K >> 6;
    int buf = 0;
    for (int it = 0; it < iters; ++it) {
        __syncthreads();               // drains DMA of this buf; orders prior reads of other buf
        if (it + 1 < iters) {
            stage32((it + 1) * 64, buf ^ 1, 0);
            stage32((it + 1) * 64 + 32, buf ^ 1, 1);
        }
#pragma unroll
        for (int ch = 0; ch < 2; ++ch) {
            const u16* As = SM + (buf * 2 + ch) * CH;
            const u16* Bs = As + BM * 32;
            short8 af[MT], bfr[NT];
#pragma unroll
            for (int mt = 0; mt < MT; ++mt) {
                int row = wm + mt * 16 + lrow;
                int p = (q + (row >> 1)) & 3;
                af[mt] = *(const short8*)&As[row * 32 + p * 8];
            }
#pragma unroll
            for (int nt = 0; nt < NT; ++nt) {
                int row = wn + nt * 16 + lrow;
                int p = (q + (row >> 1)) & 3;
                bfr[nt] = *(const short8*)&Bs[row * 32 + p * 8];
            }
#pragma unroll
            for (int mt = 0; mt < MT; ++mt)
#pragma unroll
                for (int nt = 0; nt < NT; ++nt)
                    acc[mt][nt] = __builtin_amdgcn_mfma_f32_16x16x32_bf16(af[mt], bfr[nt], acc[mt][nt], 0, 0, 0);
        }
        buf ^= 1;
    }

#pragma unroll
    for (int mt = 0; mt < MT; ++mt) {
        int mb = m0 + wm + mt * 16 + q * 4;
#pragma unroll
        for (int nt = 0; nt < NT; ++nt) {
            int n = n0 + wn + nt * 16 + lrow;
            float bvv = (n < nsplit) ? bias0[n] : bias1[n - nsplit];
#pragma unroll
            for (int i = 0; i < 4; ++i) {
                float v = acc[mt][nt][i] + bvv;
                if (relu) v = fmaxf(v, 0.f);
                if (resbf) v += b2f(resbf[(size_t)(mb + i) * N + n]);
                if (out) out[(size_t)(mb + i) * N + n] = v;
                if (outbf) outbf[(size_t)(mb + i) * N + n] = f2b(v);
            }
        }
    }
}

// ---------------- dvec[r] = t[r,:256] . d2_w + d2_b
__global__ __launch_bounds__(256) void k_dvec(const float* __restrict__ tmat, const float* __restrict__ d2w,
                                              const float* __restrict__ d2b, float* __restrict__ dvec) {
    const int r = blockIdx.x * 4 + (threadIdx.x >> 6);
    const int lane = threadIdx.x & 63;
    const float* row = tmat + (size_t)r * 256;
    float acc = 0.f;
    for (int f = lane; f < 256; f += 64) acc += row[f] * d2w[f];
    for (int off = 32; off; off >>= 1) acc += __shfl_xor(acc, off);
    if (lane == 0) dvec[r] = acc + d2b[0];
}

// ---------------- channel decoder + abs
__global__ __launch_bounds__(64) void k_final(const float* __restrict__ dvec, const float* __restrict__ c1w,
                                              const float* __restrict__ c1b, const float* __restrict__ c2w,
                                              const float* __restrict__ c2b, float* __restrict__ out) {
    const int b = blockIdx.x;
    const int f = threadIdx.x;
    float part = 0.f;
    if (f < 32) {
        float acc = c1b[f];
        const float* dr = dvec + b * 64;
        for (int c = 0; c < 64; ++c) acc += dr[c] * c1w[f * 64 + c];
        acc = acc > 0.f ? acc : 0.f;
        part = acc * c2w[f];
    }
    for (int off = 32; off; off >>= 1) part += __shfl_xor(part, off);
    if (f == 0) out[b] = fabsf(part + c2b[0]);
}

extern "C" void kernel_launch(void* const* d_in, const int* in_sizes, int n_in,
                              void* d_out, int out_size, void* d_ws, size_t ws_size,
                              hipStream_t stream) {
    const float* x     = (const float*)d_in[0];
    const float* occ   = (const float*)d_in[1];
    const float* projw = (const float*)d_in[2];
    const float* projb = (const float*)d_in[3];
    const float* ll1w  = (const float*)d_in[4];
    const float* ll1b  = (const float*)d_in[5];
    const float* ll2w  = (const float*)d_in[6];
    const float* ll2b  = (const float*)d_in[7];
    const float* g1w   = (const float*)d_in[8];
    const float* g1b   = (const float*)d_in[9];
    const float* g2w   = (const float*)d_in[10];
    const float* g2b   = (const float*)d_in[11];
    const float* gcw   = (const float*)d_in[12];
    const float* gcb   = (const float*)d_in[13];
    const float* taw   = (const float*)d_in[14];
    const float* tab   = (const float*)d_in[15];
    const float* d1w   = (const float*)d_in[16];
    const float* d1b   = (const float*)d_in[17];
    const float* d2w   = (const float*)d_in[18];
    const float* d2b   = (const float*)d_in[19];
    const float* c1w   = (const float*)d_in[20];
    const float* c1b   = (const float*)d_in[21];
    const float* c2w   = (const float*)d_in[22];
    const float* c2b   = (const float*)d_in[23];

    const size_t MR = (size_t)16384 * 512;
    float* ws   = (float*)d_ws;
    float* x2T  = ws;                          // d1 output (fp32), 16384*256
    float* vbuf = x2T + (size_t)16384 * 256;   // 16384*128
    float* proj = vbuf + (size_t)16384 * 128;
    float* dvec = proj + 16384;
    u16* bfb     = (u16*)(dvec + 16384);
    u16* xmA_bf  = bfb;
    u16* xmB_bf  = xmA_bf + MR;
    u16* x1_bf   = xmB_bf + MR;
    u16* x2_bf   = x1_bf + MR;
    u16* x1T_bf  = x2_bf + MR;                // ta output (bf16 only)
    u16* adpT_bf = x1T_bf + MR;               // 16384*64
    u16* ll1w_bf = adpT_bf + (size_t)16384 * 64;
    u16* ll2w_bf = ll1w_bf + 98304;
    u16* gcw_bf  = ll2w_bf + 98304;           // 3*512*1536
    u16* taw_bf  = gcw_bf + 2359296;
    u16* d1w_bf  = taw_bf + 262144;

    k_cvt<<<96,   256, 0, stream>>>(ll1w, ll1w_bf, 98304 / 4);
    k_cvt<<<96,   256, 0, stream>>>(ll2w, ll2w_bf, 98304 / 4);
    k_cvt<<<2304, 256, 0, stream>>>(gcw,  gcw_bf,  2359296 / 4);
    k_cvt<<<256,  256, 0, stream>>>(taw,  taw_bf,  262144 / 4);
    k_cvt<<<128,  256, 0, stream>>>(d1w,  d1w_bf,  131072 / 4);

    k_transpose<<<dim3(8, 256), 256, 0, stream>>>(x, xmA_bf);
    k_proj<<<256, 64, 0, stream>>>(occ, projw, projb, proj);

    u16* cur_bf = xmA_bf;
    u16* nxt_bf = xmB_bf;
    for (int l = 0; l < 3; ++l) {
        mfma_gemm<64, 64><<<dim3(256, 2), 256, 0, stream>>>(
            cur_bf, nullptr, nullptr,
            ll1w_bf + (size_t)l * 32768, ll2w_bf + (size_t)l * 32768, 64,
            ll1b + l * 64, ll2b + l * 64, nullptr, vbuf, nullptr, 128, 512, 0);
        k_pm<<<16384, 64, 0, stream>>>(cur_bf, g1w + l * 576, g1b + l, g2w + l * 576, g2b + l, proj, vbuf);
        k_adp<<<256, 256, 0, stream>>>(vbuf, adpT_bf);
        k_nconv2<<<dim3(4, 256), 256, 0, stream>>>(cur_bf, adpT_bf, x1_bf, x2_bf);
        mfma_gemm<128, 64><<<dim3(128, 8), 256, 0, stream>>>(
            cur_bf, x1_bf, x2_bf,
            gcw_bf + (size_t)l * 786432, gcw_bf + (size_t)l * 786432, 512,
            gcb + l * 512, gcb + l * 512, (l > 0 ? cur_bf : nullptr), nullptr, nxt_bf, 512, 1536, 1);
        { u16* tb = cur_bf; cur_bf = nxt_bf; nxt_bf = tb; }
    }
    // temporal_agg: bf16-only output
    mfma_gemm<128, 64><<<dim3(128, 8), 256, 0, stream>>>(
        cur_bf, nullptr, nullptr, taw_bf, taw_bf, 512, tab, tab, nullptr, nullptr, x1T_bf, 512, 512, 0);
    // decoder1: fp32 output for k_dvec
    mfma_gemm<64, 64><<<dim3(256, 4), 256, 0, stream>>>(
        x1T_bf, nullptr, nullptr, d1w_bf, d1w_bf, 256, d1b, d1b, nullptr, x2T, nullptr, 256, 512, 1);
    k_dvec<<<4096, 256, 0, stream>>>(x2T, d2w, d2b, dvec);
    k_final<<<256, 64, 0, stream>>>(dvec, c1w, c1b, c2w, c2b, (float*)d_out);
}

// Round 9
// 468.937 us; speedup vs baseline: 1.0413x; 1.0413x over previous
//
#include <hip/hip_runtime.h>

typedef unsigned short u16;
typedef __attribute__((ext_vector_type(8))) short short8;   // 8 bf16
typedef __attribute__((ext_vector_type(4))) float f32x4;

// B=256, N=H=512, C=A=64, L=3, FC=256, FFC=32.  M := B*C = 16384 rows of xm.
// All state bf16 (validated R8: absmax 0.0); fp32 only for d1 output tail.

__device__ __forceinline__ u16 f2b(float f) {
    union { float f; unsigned int i; } v; v.f = f;
    unsigned int x = v.i;
    x += 0x7fffu + ((x >> 16) & 1u);   // RNE
    return (u16)(x >> 16);
}
__device__ __forceinline__ float b2f(u16 u) {
    union { unsigned int i; float f; } v;
    v.i = ((unsigned int)u) << 16;
    return v.f;
}
// async global->LDS, 16B per lane; LDS dest = wave-uniform base + lane*16
__device__ __forceinline__ void gl_lds16(const u16* g, u16* l) {
    __builtin_amdgcn_global_load_lds((__attribute__((address_space(1))) void*)(u16*)g,
                                     (__attribute__((address_space(3))) void*)l, 16, 0, 0);
}

// ---------------- single fused fp32->bf16 weight conversion into contiguous arena
// arena layout (shorts): [ll1w 98304 | ll2w 98304 | gcw 2359296 | taw 262144 | d1w 131072]
__global__ __launch_bounds__(256) void k_cvt_all(const float* __restrict__ ll1w, const float* __restrict__ ll2w,
                                                 const float* __restrict__ gcw, const float* __restrict__ taw,
                                                 const float* __restrict__ d1w, u16* __restrict__ dst) {
    int i = blockIdx.x * 256 + threadIdx.x;   // uint4 index, total 737280
    if (i >= 737280) return;
    const float* src;
    int off;
    if (i < 24576)       { src = ll1w; off = i; }
    else if (i < 49152)  { src = ll2w; off = i - 24576; }
    else if (i < 638976) { src = gcw;  off = i - 49152; }
    else if (i < 704512) { src = taw;  off = i - 638976; }
    else                 { src = d1w;  off = i - 704512; }
    float4 v = ((const float4*)src)[off];
    ushort4 o; o.x = f2b(v.x); o.y = f2b(v.y); o.z = f2b(v.z); o.w = f2b(v.w);
    ((ushort4*)dst)[i] = o;
}

// ---------------- transpose: x[b,n,c] -> xmb[(b*64+c)*512+n] bf16
__global__ __launch_bounds__(256) void k_transpose(const float* __restrict__ x, u16* __restrict__ xmb) {
    __shared__ float tile[64][65];
    const int b  = blockIdx.y;
    const int n0 = blockIdx.x * 64;
    const int t  = threadIdx.x;
    const int c  = t & 63;
    const int dn = t >> 6;
#pragma unroll
    for (int i = 0; i < 16; ++i) {
        int nl = dn + i * 4;
        tile[c][nl] = x[((size_t)b * 512 + n0 + nl) * 64 + c];
    }
    __syncthreads();
    const int nl = t & 63;
    const int cb = (t >> 6) * 16;
#pragma unroll
    for (int i = 0; i < 16; ++i) {
        int c2 = cb + i;
        xmb[((size_t)b * 64 + c2) * 512 + n0 + nl] = f2b(tile[c2][nl]);
    }
}

// ---------------- proj[b,a]
__global__ __launch_bounds__(64) void k_proj(const float* __restrict__ occ, const float* __restrict__ pw,
                                             const float* __restrict__ pb, float* __restrict__ proj) {
    const int b = blockIdx.x;
    const int a = threadIdx.x;
    const float* ob = occ + (size_t)b * 512;
    const float* wr = pw + (size_t)a * 512;
    float acc = 0.f;
    for (int n = 0; n < 512; ++n) acc += ob[n] * wr[n];
    proj[b * 64 + a] = acc + pb[a];
}

// ---------------- fused gates + P + adp (per b): m1/m2 gate dots, P softmax (LDS only), adjacency
__global__ __launch_bounds__(256) void k_pmadp(const u16* __restrict__ xmb, const float* __restrict__ vbuf,
                                               const float* __restrict__ g1w, const float* __restrict__ g1b,
                                               const float* __restrict__ g2w, const float* __restrict__ g2b,
                                               const float* __restrict__ proj, u16* __restrict__ adpT) {
    __shared__ float g1s[576], g2s[576], prj[64];
    __shared__ float P1s[64][64];
    __shared__ float P2s[64][65];
    __shared__ __align__(16) u16 Tl[64 * 72];
    const int b = blockIdx.x;
    const int t = threadIdx.x;
    const int lane = t & 63, w = t >> 6;
    if (t < 144) {
        *(float4*)&g1s[t * 4] = *(const float4*)(g1w + t * 4);
        *(float4*)&g2s[t * 4] = *(const float4*)(g2w + t * 4);
    }
    if (t >= 240) *(float4*)&prj[(t - 240) * 4] = *(const float4*)(proj + b * 64 + (t - 240) * 4);
    __syncthreads();
    float S1 = 0.f, G2 = 0.f;
#pragma unroll
    for (int a = 0; a < 64; ++a) { S1 += prj[a] * g1s[512 + a]; G2 += g2s[512 + a]; }
    const float b1 = g1b[0], b2v = g2b[0];
#pragma unroll 4
    for (int ci = 0; ci < 16; ++ci) {
        int c = w + ci * 4;
        int r = b * 64 + c;
        uint4 xv = *(const uint4*)(xmb + (size_t)r * 512 + lane * 8);
        const u16* xp = (const u16*)&xv;
        float a1 = 0.f, a2 = 0.f;
#pragma unroll
        for (int e = 0; e < 8; ++e) {
            float xf = b2f(xp[e]);
            a1 += xf * g1s[lane * 8 + e];
            a2 += xf * g2s[lane * 8 + e];
        }
        for (int off = 32; off; off >>= 1) { a1 += __shfl_xor(a1, off); a2 += __shfl_xor(a2, off); }
        float m1 = tanhf(a1 + S1 + b1);          m1 = m1 > 0.f ? m1 : 0.f;
        float m2 = tanhf(a2 + prj[c] * G2 + b2v); m2 = m2 > 0.f ? m2 : 0.f;
        float s1 = fmaxf(m1 * vbuf[(size_t)r * 128 + lane], 0.f);
        float s2 = fmaxf(m2 * vbuf[(size_t)r * 128 + 64 + lane], 0.f);
        float mx1 = s1, mx2 = s2;
        for (int off = 32; off; off >>= 1) { mx1 = fmaxf(mx1, __shfl_xor(mx1, off)); mx2 = fmaxf(mx2, __shfl_xor(mx2, off)); }
        float e1 = expf(s1 - mx1), e2 = expf(s2 - mx2);
        float su1 = e1, su2 = e2;
        for (int off = 32; off; off >>= 1) { su1 += __shfl_xor(su1, off); su2 += __shfl_xor(su2, off); }
        P1s[c][lane] = prj[lane] + e1 / su1;
        P2s[c][lane] = prj[c]    + e2 / su2;
    }
    __syncthreads();
    // adp[c][v] = softmax_v relu(P1[c].P2[v]); store transposed Tl[v][c] -> adpT
    for (int ci = 0; ci < 16; ++ci) {
        int c = w + ci * 4;
        float s = 0.f;
        for (int a = 0; a < 64; ++a) s += P1s[c][a] * P2s[lane][a];
        s = fmaxf(s, 0.f);
        float mx = s;
        for (int off = 32; off; off >>= 1) mx = fmaxf(mx, __shfl_xor(mx, off));
        float e = expf(s - mx);
        float su = e;
        for (int off = 32; off; off >>= 1) su += __shfl_xor(su, off);
        Tl[lane * 72 + c] = f2b(e / su);
    }
    __syncthreads();
    const int v = t >> 2, ck = (t & 3) * 16;
    u16* dst = adpT + ((size_t)b * 64 + v) * 64 + ck;
    *(uint4*)dst       = *(const uint4*)&Tl[v * 72 + ck];
    *(uint4*)(dst + 8) = *(const uint4*)&Tl[v * 72 + ck + 8];
}

// ---------------- fused double nconv via MFMA: x1 = adp^T X, x2 = adp^T x1 (per b, n-tile 128)
__global__ __launch_bounds__(256) void k_nconv2(const u16* __restrict__ Xbf, const u16* __restrict__ adpT,
                                                u16* __restrict__ x1bf, u16* __restrict__ x2bf) {
    __shared__ __align__(16) u16 Ts[64 * 72];
    __shared__ __align__(16) u16 Xs[128 * 72];
    const int b  = blockIdx.y;
    const int n0 = blockIdx.x * 128;
    const int t  = threadIdx.x;
    const int lane = t & 63, w = t >> 6;
    const int lrow = lane & 15, q = lane >> 4;
    const int wn = w * 32;

    {
        int v = t >> 2, ck = (t & 3) * 8;
        const u16* src = adpT + ((size_t)b * 64 + v) * 64;
        *(uint4*)&Ts[v * 72 + ck]      = *(const uint4*)(src + ck);
        *(uint4*)&Ts[v * 72 + ck + 32] = *(const uint4*)(src + ck + 32);
    }
    {
        int c = t >> 2;
        const u16* xr = Xbf + ((size_t)b * 64 + c) * 512 + n0;
#pragma unroll
        for (int j = 0; j < 4; ++j) {
            int nn = j * 32 + (t & 3) * 8;
            uint4 vv = *(const uint4*)(xr + nn);
            const u16* pv = (const u16*)&vv;
#pragma unroll
            for (int e = 0; e < 8; ++e) Xs[(nn + e) * 72 + c] = pv[e];
        }
    }
    __syncthreads();

    const f32x4 zero = {0.f, 0.f, 0.f, 0.f};
    f32x4 acc[4][2];
#pragma unroll
    for (int mt = 0; mt < 4; ++mt)
#pragma unroll
        for (int nt = 0; nt < 2; ++nt) acc[mt][nt] = zero;

#pragma unroll
    for (int ks = 0; ks < 2; ++ks) {
        short8 af[4], bfr[2];
#pragma unroll
        for (int mt = 0; mt < 4; ++mt) af[mt]  = *(const short8*)&Ts[(mt * 16 + lrow) * 72 + ks * 32 + q * 8];
#pragma unroll
        for (int nt = 0; nt < 2; ++nt) bfr[nt] = *(const short8*)&Xs[(wn + nt * 16 + lrow) * 72 + ks * 32 + q * 8];
#pragma unroll
        for (int mt = 0; mt < 4; ++mt)
#pragma unroll
            for (int nt = 0; nt < 2; ++nt)
                acc[mt][nt] = __builtin_amdgcn_mfma_f32_16x16x32_bf16(af[mt], bfr[nt], acc[mt][nt], 0, 0, 0);
    }
    __syncthreads();

#pragma unroll
    for (int mt = 0; mt < 4; ++mt)
#pragma unroll
        for (int nt = 0; nt < 2; ++nt) {
            int nl = wn + nt * 16 + lrow;
            ushort4 u;
            u.x = f2b(acc[mt][nt][0]); u.y = f2b(acc[mt][nt][1]);
            u.z = f2b(acc[mt][nt][2]); u.w = f2b(acc[mt][nt][3]);
            *(ushort4*)&Xs[nl * 72 + mt * 16 + q * 4] = u;
#pragma unroll
            for (int i = 0; i < 4; ++i)
                x1bf[((size_t)(b * 64 + mt * 16 + q * 4 + i)) * 512 + n0 + nl] = ((const u16*)&u)[i];
        }
    __syncthreads();

    f32x4 acc2[4][2];
#pragma unroll
    for (int mt = 0; mt < 4; ++mt)
#pragma unroll
        for (int nt = 0; nt < 2; ++nt) acc2[mt][nt] = zero;
#pragma unroll
    for (int ks = 0; ks < 2; ++ks) {
        short8 af[4], bfr[2];
#pragma unroll
        for (int mt = 0; mt < 4; ++mt) af[mt]  = *(const short8*)&Ts[(mt * 16 + lrow) * 72 + ks * 32 + q * 8];
#pragma unroll
        for (int nt = 0; nt < 2; ++nt) bfr[nt] = *(const short8*)&Xs[(wn + nt * 16 + lrow) * 72 + ks * 32 + q * 8];
#pragma unroll
        for (int mt = 0; mt < 4; ++mt)
#pragma unroll
            for (int nt = 0; nt < 2; ++nt)
                acc2[mt][nt] = __builtin_amdgcn_mfma_f32_16x16x32_bf16(af[mt], bfr[nt], acc2[mt][nt], 0, 0, 0);
    }
#pragma unroll
    for (int mt = 0; mt < 4; ++mt)
#pragma unroll
        for (int nt = 0; nt < 2; ++nt) {
            int nl = wn + nt * 16 + lrow;
#pragma unroll
            for (int i = 0; i < 4; ++i)
                x2bf[((size_t)(b * 64 + mt * 16 + q * 4 + i)) * 512 + n0 + nl] = f2b(acc2[mt][nt][i]);
        }
}

// ---------------- MFMA GEMM (R7 structure): BK=32 double-buffered global_load_lds, swizzled rows.
// barrier(drains DMA of cur) -> issue DMA(next)->other buf -> compute(cur). 1 barrier/iter.
template<int BM, int BN>
__global__ __launch_bounds__(256) void mfma_gemm(
    const u16* __restrict__ A0, const u16* __restrict__ A1, const u16* __restrict__ A2,
    const u16* __restrict__ W0, const u16* __restrict__ W1, int nsplit,
    const float* __restrict__ bias0, const float* __restrict__ bias1,
    const u16* __restrict__ resbf, float* __restrict__ out, u16* __restrict__ outbf,
    int N, int K, int relu)
{
    constexpr int MT = BM / 32;
    constexpr int NT = BN / 32;
    constexpr int AI = BM / 16;
    constexpr int BI = BN / 16;
    constexpr int TILE = (BM + BN) * 32;
    __shared__ __align__(16) u16 SM[2 * TILE];
    const int t    = threadIdx.x;
    const int m0   = blockIdx.x * BM;
    const int n0   = blockIdx.y * BN;
    const int lane = t & 63;
    const int w    = t >> 6;
    const int wm   = (w >> 1) * (BM / 2);
    const int wn   = (w & 1) * (BN / 2);
    const int lrow = lane & 15;
    const int q    = lane >> 4;
    const int sr16 = lane >> 2;
    const int sp   = lane & 3;

    auto stage = [&](int k0, int buf) {
        u16* As = SM + buf * TILE;
        u16* Bs = As + BM * 32;
        const u16* Abase = A0;
        int kloc = k0;
        if (K > 512) {
            int seg = k0 >> 9;
            Abase = (seg == 0) ? A0 : ((seg == 1) ? A1 : A2);
            kloc = k0 & 511;
        }
#pragma unroll
        for (int jj = 0; jj < AI / 4; ++jj) {
            int j = jj * 4 + w;
            int row = j * 16 + sr16;
            int c = (sp - (row >> 1)) & 3;
            gl_lds16(Abase + (size_t)(m0 + row) * 512 + kloc + c * 8, As + j * 512);
        }
#pragma unroll
        for (int jj = 0; jj < BI / 4; ++jj) {
            int j = jj * 4 + w;
            int row = j * 16 + sr16;
            int n = n0 + row;
            const u16* wr = (n < nsplit) ? (W0 + (size_t)n * K) : (W1 + (size_t)(n - nsplit) * K);
            int c = (sp - (row >> 1)) & 3;
            gl_lds16(wr + k0 + c * 8, Bs + j * 512);
        }
    };

    const f32x4 zero = {0.f, 0.f, 0.f, 0.f};
    f32x4 acc[MT][NT];
#pragma unroll
    for (int i = 0; i < MT; ++i)
#pragma unroll
        for (int j = 0; j < NT; ++j) acc[i][j] = zero;

    stage(0, 0);
    const int iters = K >> 5;
    int buf = 0;
    for (int it = 0; it < iters; ++it) {
        __syncthreads();
        if (it + 1 < iters) stage((it + 1) * 32, buf ^ 1);
        const u16* As = SM + buf * TILE;
        const u16* Bs = As + BM * 32;
        short8 af[MT], bfr[NT];
#pragma unroll
        for (int mt = 0; mt < MT; ++mt) {
            int row = wm + mt * 16 + lrow;
            int p = (q + (row >> 1)) & 3;
            af[mt] = *(const short8*)&As[row * 32 + p * 8];
        }
#pragma unroll
        for (int nt = 0; nt < NT; ++nt) {
            int row = wn + nt * 16 + lrow;
            int p = (q + (row >> 1)) & 3;
            bfr[nt] = *(const short8*)&Bs[row * 32 + p * 8];
        }
#pragma unroll
        for (int mt = 0; mt < MT; ++mt)
#pragma unroll
            for (int nt = 0; nt < NT; ++nt)
                acc[mt][nt] = __builtin_amdgcn_mfma_f32_16x16x32_bf16(af[mt], bfr[nt], acc[mt][nt], 0, 0, 0);
        buf ^= 1;
    }

#pragma unroll
    for (int mt = 0; mt < MT; ++mt) {
        int mb = m0 + wm + mt * 16 + q * 4;
#pragma unroll
        for (int nt = 0; nt < NT; ++nt) {
            int n = n0 + wn + nt * 16 + lrow;
            float bvv = (n < nsplit) ? bias0[n] : bias1[n - nsplit];
#pragma unroll
            for (int i = 0; i < 4; ++i) {
                float v = acc[mt][nt][i] + bvv;
                if (relu) v = fmaxf(v, 0.f);
                if (resbf) v += b2f(resbf[(size_t)(mb + i) * N + n]);
                if (out) out[(size_t)(mb + i) * N + n] = v;
                if (outbf) outbf[(size_t)(mb + i) * N + n] = f2b(v);
            }
        }
    }
}

// ---------------- fused decoder tail (per b): dvec = x2T.d2w+d2b over 64 rows, then c1/c2 + abs
__global__ __launch_bounds__(256) void k_dec(const float* __restrict__ x2T, const float* __restrict__ d2w,
                                             const float* __restrict__ d2b, const float* __restrict__ c1w,
                                             const float* __restrict__ c1b, const float* __restrict__ c2w,
                                             const float* __restrict__ c2b, float* __restrict__ out) {
    __shared__ float dv[64];
    __shared__ float d2s[256];
    const int b = blockIdx.x, t = threadIdx.x;
    const int lane = t & 63, w = t >> 6;
    if (t < 64) *(float4*)&d2s[t * 4] = *(const float4*)(d2w + t * 4);
    __syncthreads();
#pragma unroll 4
    for (int ci = 0; ci < 16; ++ci) {
        int c = w + ci * 4;
        const float* row = x2T + (size_t)(b * 64 + c) * 256;
        float acc = row[lane] * d2s[lane] + row[64 + lane] * d2s[64 + lane]
                  + row[128 + lane] * d2s[128 + lane] + row[192 + lane] * d2s[192 + lane];
        for (int off = 32; off; off >>= 1) acc += __shfl_xor(acc, off);
        if (lane == 0) dv[c] = acc + d2b[0];
    }
    __syncthreads();
    if (w == 0) {
        float part = 0.f;
        if (lane < 32) {
            float acc = c1b[lane];
            for (int c = 0; c < 64; ++c) acc += dv[c] * c1w[lane * 64 + c];
            part = fmaxf(acc, 0.f) * c2w[lane];
        }
        for (int off = 32; off; off >>= 1) part += __shfl_xor(part, off);
        if (lane == 0) out[b] = fabsf(part + c2b[0]);
    }
}

extern "C" void kernel_launch(void* const* d_in, const int* in_sizes, int n_in,
                              void* d_out, int out_size, void* d_ws, size_t ws_size,
                              hipStream_t stream) {
    const float* x     = (const float*)d_in[0];
    const float* occ   = (const float*)d_in[1];
    const float* projw = (const float*)d_in[2];
    const float* projb = (const float*)d_in[3];
    const float* ll1w  = (const float*)d_in[4];
    const float* ll1b  = (const float*)d_in[5];
    const float* ll2w  = (const float*)d_in[6];
    const float* ll2b  = (const float*)d_in[7];
    const float* g1w   = (const float*)d_in[8];
    const float* g1b   = (const float*)d_in[9];
    const float* g2w   = (const float*)d_in[10];
    const float* g2b   = (const float*)d_in[11];
    const float* gcw   = (const float*)d_in[12];
    const float* gcb   = (const float*)d_in[13];
    const float* taw   = (const float*)d_in[14];
    const float* tab   = (const float*)d_in[15];
    const float* d1w   = (const float*)d_in[16];
    const float* d1b   = (const float*)d_in[17];
    const float* d2w   = (const float*)d_in[18];
    const float* d2b   = (const float*)d_in[19];
    const float* c1w   = (const float*)d_in[20];
    const float* c1b   = (const float*)d_in[21];
    const float* c2w   = (const float*)d_in[22];
    const float* c2b   = (const float*)d_in[23];

    const size_t MR = (size_t)16384 * 512;
    float* ws   = (float*)d_ws;
    float* x2T  = ws;                          // d1 output (fp32), 16384*256
    float* vbuf = x2T + (size_t)16384 * 256;   // 16384*128 (ll output)
    float* proj = vbuf + (size_t)16384 * 128;
    u16* bfb     = (u16*)(proj + 16384);
    u16* xmA_bf  = bfb;
    u16* xmB_bf  = xmA_bf + MR;
    u16* x1_bf   = xmB_bf + MR;
    u16* x2_bf   = x1_bf + MR;
    u16* x1T_bf  = x2_bf + MR;                // ta output (bf16 only)
    u16* adpT_bf = x1T_bf + MR;               // 16384*64
    u16* wb      = adpT_bf + (size_t)16384 * 64;   // contiguous bf16 weight arena
    u16* ll1w_bf = wb;                        // 98304
    u16* ll2w_bf = ll1w_bf + 98304;           // 98304
    u16* gcw_bf  = ll2w_bf + 98304;           // 2359296
    u16* taw_bf  = gcw_bf + 2359296;          // 262144
    u16* d1w_bf  = taw_bf + 262144;           // 131072

    k_cvt_all<<<2880, 256, 0, stream>>>(ll1w, ll2w, gcw, taw, d1w, wb);
    k_transpose<<<dim3(8, 256), 256, 0, stream>>>(x, xmA_bf);
    k_proj<<<256, 64, 0, stream>>>(occ, projw, projb, proj);

    u16* cur_bf = xmA_bf;
    u16* nxt_bf = xmB_bf;
    for (int l = 0; l < 3; ++l) {
        mfma_gemm<64, 64><<<dim3(256, 2), 256, 0, stream>>>(
            cur_bf, nullptr, nullptr,
            ll1w_bf + (size_t)l * 32768, ll2w_bf + (size_t)l * 32768, 64,
            ll1b + l * 64, ll2b + l * 64, nullptr, vbuf, nullptr, 128, 512, 0);
        k_pmadp<<<256, 256, 0, stream>>>(cur_bf, vbuf, g1w + l * 576, g1b + l,
                                         g2w + l * 576, g2b + l, proj, adpT_bf);
        k_nconv2<<<dim3(4, 256), 256, 0, stream>>>(cur_bf, adpT_bf, x1_bf, x2_bf);
        mfma_gemm<128, 64><<<dim3(128, 8), 256, 0, stream>>>(
            cur_bf, x1_bf, x2_bf,
            gcw_bf + (size_t)l * 786432, gcw_bf + (size_t)l * 786432, 512,
            gcb + l * 512, gcb + l * 512, (l > 0 ? cur_bf : nullptr), nullptr, nxt_bf, 512, 1536, 1);
        { u16* tb = cur_bf; cur_bf = nxt_bf; nxt_bf = tb; }
    }
    // temporal_agg: bf16-only output
    mfma_gemm<128, 64><<<dim3(128, 8), 256, 0, stream>>>(
        cur_bf, nullptr, nullptr, taw_bf, taw_bf, 512, tab, tab, nullptr, nullptr, x1T_bf, 512, 512, 0);
    // decoder1: fp32 output for k_dec
    mfma_gemm<64, 64><<<dim3(256, 4), 256, 0, stream>>>(
        x1T_bf, nullptr, nullptr, d1w_bf, d1w_bf, 256, d1b, d1b, nullptr, x2T, nullptr, 256, 512, 1);
    k_dec<<<256, 256, 0, stream>>>(x2T, d2w, d2b, c1w, c1b, c2w, c2b, (float*)d_out);
}

// Round 10
// 418.702 us; speedup vs baseline: 1.1662x; 1.1200x over previous
//
#include <hip/hip_runtime.h>

typedef unsigned short u16;
typedef __attribute__((ext_vector_type(8))) short short8;   // 8 bf16
typedef __attribute__((ext_vector_type(4))) float f32x4;

// B=256, N=H=512, C=A=64, L=3, FC=256, FFC=32.  M := B*C = 16384 rows of xm.
// All state bf16; fp32 only for ll->P路 (vbuf) and d1 output tail.

__device__ __forceinline__ u16 f2b(float f) {
    union { float f; unsigned int i; } v; v.f = f;
    unsigned int x = v.i;
    x += 0x7fffu + ((x >> 16) & 1u);   // RNE
    return (u16)(x >> 16);
}
__device__ __forceinline__ float b2f(u16 u) {
    union { unsigned int i; float f; } v;
    v.i = ((unsigned int)u) << 16;
    return v.f;
}
// async global->LDS, 16B per lane; LDS dest = wave-uniform base + lane*16
__device__ __forceinline__ void gl_lds16(const u16* g, u16* l) {
    __builtin_amdgcn_global_load_lds((__attribute__((address_space(1))) void*)(u16*)g,
                                     (__attribute__((address_space(3))) void*)l, 16, 0, 0);
}

// ---------------- single fused fp32->bf16 weight conversion into contiguous arena
__global__ __launch_bounds__(256) void k_cvt_all(const float* __restrict__ ll1w, const float* __restrict__ ll2w,
                                                 const float* __restrict__ gcw, const float* __restrict__ taw,
                                                 const float* __restrict__ d1w, u16* __restrict__ dst) {
    int i = blockIdx.x * 256 + threadIdx.x;   // uint4 index, total 737280
    if (i >= 737280) return;
    const float* src;
    int off;
    if (i < 24576)       { src = ll1w; off = i; }
    else if (i < 49152)  { src = ll2w; off = i - 24576; }
    else if (i < 638976) { src = gcw;  off = i - 49152; }
    else if (i < 704512) { src = taw;  off = i - 638976; }
    else                 { src = d1w;  off = i - 704512; }
    float4 v = ((const float4*)src)[off];
    ushort4 o; o.x = f2b(v.x); o.y = f2b(v.y); o.z = f2b(v.z); o.w = f2b(v.w);
    ((ushort4*)dst)[i] = o;
}

// ---------------- transpose: x[b,n,c] -> xmb[(b*64+c)*512+n] bf16
__global__ __launch_bounds__(256) void k_transpose(const float* __restrict__ x, u16* __restrict__ xmb) {
    __shared__ float tile[64][65];
    const int b  = blockIdx.y;
    const int n0 = blockIdx.x * 64;
    const int t  = threadIdx.x;
    const int c  = t & 63;
    const int dn = t >> 6;
#pragma unroll
    for (int i = 0; i < 16; ++i) {
        int nl = dn + i * 4;
        tile[c][nl] = x[((size_t)b * 512 + n0 + nl) * 64 + c];
    }
    __syncthreads();
    const int nl = t & 63;
    const int cb = (t >> 6) * 16;
#pragma unroll
    for (int i = 0; i < 16; ++i) {
        int c2 = cb + i;
        xmb[((size_t)b * 64 + c2) * 512 + n0 + nl] = f2b(tile[c2][nl]);
    }
}

// ---------------- proj[b,a]
__global__ __launch_bounds__(64) void k_proj(const float* __restrict__ occ, const float* __restrict__ pw,
                                             const float* __restrict__ pb, float* __restrict__ proj) {
    const int b = blockIdx.x;
    const int a = threadIdx.x;
    const float* ob = occ + (size_t)b * 512;
    const float* wr = pw + (size_t)a * 512;
    float acc = 0.f;
    for (int n = 0; n < 512; ++n) acc += ob[n] * wr[n];
    proj[b * 64 + a] = acc + pb[a];
}

// ---------------- gates + P per row r=(b,c): write P1,P2 bf16 to Pb[r*128 + {a, 64+a}]
__global__ __launch_bounds__(64) void k_pm(const u16* __restrict__ xmb, const float* __restrict__ vb,
                                           const float* __restrict__ g1w, const float* __restrict__ g1b,
                                           const float* __restrict__ g2w, const float* __restrict__ g2b,
                                           const float* __restrict__ proj, u16* __restrict__ Pb) {
    const int r = blockIdx.x;
    const int b = r >> 6, c = r & 63;
    const int lane = threadIdx.x;
    uint4 xv = *(const uint4*)(xmb + (size_t)r * 512 + lane * 8);
    const u16* xp = (const u16*)&xv;
    float4 w1a = *(const float4*)(g1w + lane * 8);
    float4 w1b = *(const float4*)(g1w + lane * 8 + 4);
    float4 w2a = *(const float4*)(g2w + lane * 8);
    float4 w2b = *(const float4*)(g2w + lane * 8 + 4);
    float g1v[8] = {w1a.x, w1a.y, w1a.z, w1a.w, w1b.x, w1b.y, w1b.z, w1b.w};
    float g2v[8] = {w2a.x, w2a.y, w2a.z, w2a.w, w2b.x, w2b.y, w2b.z, w2b.w};
    float a1 = 0.f, a2 = 0.f;
#pragma unroll
    for (int e = 0; e < 8; ++e) {
        float xf = b2f(xp[e]);
        a1 += xf * g1v[e];
        a2 += xf * g2v[e];
    }
    a1 += proj[b * 64 + lane] * g1w[512 + lane];   // AATE part
    a2 += proj[b * 64 + c]    * g2w[512 + lane];   // AATE_T part
    for (int off = 32; off; off >>= 1) { a1 += __shfl_xor(a1, off); a2 += __shfl_xor(a2, off); }
    float m1 = tanhf(a1 + g1b[0]); m1 = m1 > 0.f ? m1 : 0.f;
    float m2 = tanhf(a2 + g2b[0]); m2 = m2 > 0.f ? m2 : 0.f;
    const int a = lane;
    float s1 = fmaxf(m1 * vb[(size_t)r * 128 + a], 0.f);
    float s2 = fmaxf(m2 * vb[(size_t)r * 128 + 64 + a], 0.f);
    float mx1 = s1, mx2 = s2;
    for (int off = 32; off; off >>= 1) { mx1 = fmaxf(mx1, __shfl_xor(mx1, off)); mx2 = fmaxf(mx2, __shfl_xor(mx2, off)); }
    float e1 = expf(s1 - mx1), e2 = expf(s2 - mx2);
    float su1 = e1, su2 = e2;
    for (int off = 32; off; off >>= 1) { su1 += __shfl_xor(su1, off); su2 += __shfl_xor(su2, off); }
    Pb[(size_t)r * 128 + a]      = f2b(proj[b * 64 + a] + e1 / su1);   // P1[c][a]
    Pb[(size_t)r * 128 + 64 + a] = f2b(proj[b * 64 + c] + e2 / su2);   // P2[c][a]
}

// ---------------- adjacency via MFMA (per b): S = P1.P2^T (64x64,K=64), relu+softmax_v, store adpT
__global__ __launch_bounds__(256) void k_adp2(const u16* __restrict__ Pb, u16* __restrict__ adpT) {
    __shared__ __align__(16) u16 P1s[64 * 72];
    __shared__ __align__(16) u16 P2s[64 * 72];
    __shared__ __align__(16) u16 Tl[64 * 72];
    const int b = blockIdx.x, t = threadIdx.x;
    const int lane = t & 63, w = t >> 6;
    const int lrow = lane & 15, q = lane >> 4;
    {   // stage P1/P2 (coalesced uint4)
        int rr = t >> 2, ck = (t & 3) * 16;
        const u16* src = Pb + ((size_t)b * 64 + rr) * 128;
        *(uint4*)&P1s[rr * 72 + ck]     = *(const uint4*)(src + ck);
        *(uint4*)&P1s[rr * 72 + ck + 8] = *(const uint4*)(src + ck + 8);
        *(uint4*)&P2s[rr * 72 + ck]     = *(const uint4*)(src + 64 + ck);
        *(uint4*)&P2s[rr * 72 + ck + 8] = *(const uint4*)(src + 64 + ck + 8);
    }
    __syncthreads();
    const f32x4 zero = {0.f, 0.f, 0.f, 0.f};
    // wave w computes c-rows [w*16, w*16+16), all 64 v
    short8 a0 = *(const short8*)&P1s[(w * 16 + lrow) * 72 + q * 8];
    short8 a1 = *(const short8*)&P1s[(w * 16 + lrow) * 72 + 32 + q * 8];
    f32x4 s[4];
#pragma unroll
    for (int nt = 0; nt < 4; ++nt) {
        short8 b0 = *(const short8*)&P2s[(nt * 16 + lrow) * 72 + q * 8];
        short8 b1 = *(const short8*)&P2s[(nt * 16 + lrow) * 72 + 32 + q * 8];
        s[nt] = __builtin_amdgcn_mfma_f32_16x16x32_bf16(a0, b0, zero, 0, 0, 0);
        s[nt] = __builtin_amdgcn_mfma_f32_16x16x32_bf16(a1, b1, s[nt], 0, 0, 0);
    }
    // relu + softmax over v (cols: nt x lrow-lane-group). Row i lives in 16 lanes sharing q.
    float mx[4], su[4];
#pragma unroll
    for (int i = 0; i < 4; ++i) {
        float m = 0.f;   // relu floor: all s>=0 after fmax below, softmax max >= 0
#pragma unroll
        for (int nt = 0; nt < 4; ++nt) { s[nt][i] = fmaxf(s[nt][i], 0.f); m = fmaxf(m, s[nt][i]); }
        for (int off = 1; off < 16; off <<= 1) m = fmaxf(m, __shfl_xor(m, off));
        mx[i] = m;
        float e = 0.f;
#pragma unroll
        for (int nt = 0; nt < 4; ++nt) { s[nt][i] = expf(s[nt][i] - m); e += s[nt][i]; }
        for (int off = 1; off < 16; off <<= 1) e += __shfl_xor(e, off);
        su[i] = e;
    }
#pragma unroll
    for (int nt = 0; nt < 4; ++nt)
#pragma unroll
        for (int i = 0; i < 4; ++i)
            Tl[(nt * 16 + lrow) * 72 + (w * 16 + q * 4 + i)] = f2b(s[nt][i] / su[i]);
    __syncthreads();
    const int v = t >> 2, ck = (t & 3) * 16;
    u16* dst = adpT + ((size_t)b * 64 + v) * 64 + ck;
    *(uint4*)dst       = *(const uint4*)&Tl[v * 72 + ck];
    *(uint4*)(dst + 8) = *(const uint4*)&Tl[v * 72 + ck + 8];
}

// ---------------- fused double nconv via MFMA: x1 = adp^T X, x2 = adp^T x1 (per b, n-tile 128)
__global__ __launch_bounds__(256) void k_nconv2(const u16* __restrict__ Xbf, const u16* __restrict__ adpT,
                                                u16* __restrict__ x1bf, u16* __restrict__ x2bf) {
    __shared__ __align__(16) u16 Ts[64 * 72];
    __shared__ __align__(16) u16 Xs[128 * 72];
    const int b  = blockIdx.y;
    const int n0 = blockIdx.x * 128;
    const int t  = threadIdx.x;
    const int lane = t & 63, w = t >> 6;
    const int lrow = lane & 15, q = lane >> 4;
    const int wn = w * 32;

    {
        int v = t >> 2, ck = (t & 3) * 8;
        const u16* src = adpT + ((size_t)b * 64 + v) * 64;
        *(uint4*)&Ts[v * 72 + ck]      = *(const uint4*)(src + ck);
        *(uint4*)&Ts[v * 72 + ck + 32] = *(const uint4*)(src + ck + 32);
    }
    {   // stage X transposed Xs[n][c]: 4-c packing, b64 LDS writes
        int nn8 = (t >> 4) * 8;       // n-octet 0..120
        int cb  = (t & 15) * 4;       // c-base 0..60
        const u16* xr = Xbf + ((size_t)(b * 64 + cb)) * 512 + n0 + nn8;
        uint4 v0 = *(const uint4*)(xr);
        uint4 v1 = *(const uint4*)(xr + 512);
        uint4 v2 = *(const uint4*)(xr + 1024);
        uint4 v3 = *(const uint4*)(xr + 1536);
        const u16 *p0 = (const u16*)&v0, *p1 = (const u16*)&v1, *p2 = (const u16*)&v2, *p3 = (const u16*)&v3;
#pragma unroll
        for (int e = 0; e < 8; ++e) {
            ushort4 pk; pk.x = p0[e]; pk.y = p1[e]; pk.z = p2[e]; pk.w = p3[e];
            *(ushort4*)&Xs[(nn8 + e) * 72 + cb] = pk;
        }
    }
    __syncthreads();

    const f32x4 zero = {0.f, 0.f, 0.f, 0.f};
    f32x4 acc[4][2];
#pragma unroll
    for (int mt = 0; mt < 4; ++mt)
#pragma unroll
        for (int nt = 0; nt < 2; ++nt) acc[mt][nt] = zero;

#pragma unroll
    for (int ks = 0; ks < 2; ++ks) {
        short8 af[4], bfr[2];
#pragma unroll
        for (int mt = 0; mt < 4; ++mt) af[mt]  = *(const short8*)&Ts[(mt * 16 + lrow) * 72 + ks * 32 + q * 8];
#pragma unroll
        for (int nt = 0; nt < 2; ++nt) bfr[nt] = *(const short8*)&Xs[(wn + nt * 16 + lrow) * 72 + ks * 32 + q * 8];
#pragma unroll
        for (int mt = 0; mt < 4; ++mt)
#pragma unroll
            for (int nt = 0; nt < 2; ++nt)
                acc[mt][nt] = __builtin_amdgcn_mfma_f32_16x16x32_bf16(af[mt], bfr[nt], acc[mt][nt], 0, 0, 0);
    }
    __syncthreads();

#pragma unroll
    for (int mt = 0; mt < 4; ++mt)
#pragma unroll
        for (int nt = 0; nt < 2; ++nt) {
            int nl = wn + nt * 16 + lrow;
            ushort4 u;
            u.x = f2b(acc[mt][nt][0]); u.y = f2b(acc[mt][nt][1]);
            u.z = f2b(acc[mt][nt][2]); u.w = f2b(acc[mt][nt][3]);
            *(ushort4*)&Xs[nl * 72 + mt * 16 + q * 4] = u;
#pragma unroll
            for (int i = 0; i < 4; ++i)
                x1bf[((size_t)(b * 64 + mt * 16 + q * 4 + i)) * 512 + n0 + nl] = ((const u16*)&u)[i];
        }
    __syncthreads();

    f32x4 acc2[4][2];
#pragma unroll
    for (int mt = 0; mt < 4; ++mt)
#pragma unroll
        for (int nt = 0; nt < 2; ++nt) acc2[mt][nt] = zero;
#pragma unroll
    for (int ks = 0; ks < 2; ++ks) {
        short8 af[4], bfr[2];
#pragma unroll
        for (int mt = 0; mt < 4; ++mt) af[mt]  = *(const short8*)&Ts[(mt * 16 + lrow) * 72 + ks * 32 + q * 8];
#pragma unroll
        for (int nt = 0; nt < 2; ++nt) bfr[nt] = *(const short8*)&Xs[(wn + nt * 16 + lrow) * 72 + ks * 32 + q * 8];
#pragma unroll
        for (int mt = 0; mt < 4; ++mt)
#pragma unroll
            for (int nt = 0; nt < 2; ++nt)
                acc2[mt][nt] = __builtin_amdgcn_mfma_f32_16x16x32_bf16(af[mt], bfr[nt], acc2[mt][nt], 0, 0, 0);
    }
#pragma unroll
    for (int mt = 0; mt < 4; ++mt)
#pragma unroll
        for (int nt = 0; nt < 2; ++nt) {
            int nl = wn + nt * 16 + lrow;
#pragma unroll
            for (int i = 0; i < 4; ++i)
                x2bf[((size_t)(b * 64 + mt * 16 + q * 4 + i)) * 512 + n0 + nl] = f2b(acc2[mt][nt][i]);
        }
}

// ---------------- MFMA GEMM (R7/R9 structure): BK=32 dbuf global_load_lds, swizzled rows.
template<int BM, int BN>
__global__ __launch_bounds__(256) void mfma_gemm(
    const u16* __restrict__ A0, const u16* __restrict__ A1, const u16* __restrict__ A2,
    const u16* __restrict__ W0, const u16* __restrict__ W1, int nsplit,
    const float* __restrict__ bias0, const float* __restrict__ bias1,
    const u16* __restrict__ resbf, float* __restrict__ out, u16* __restrict__ outbf,
    int N, int K, int relu)
{
    constexpr int MT = BM / 32;
    constexpr int NT = BN / 32;
    constexpr int AI = BM / 16;
    constexpr int BI = BN / 16;
    constexpr int TILE = (BM + BN) * 32;
    __shared__ __align__(16) u16 SM[2 * TILE];
    const int t    = threadIdx.x;
    const int m0   = blockIdx.x * BM;
    const int n0   = blockIdx.y * BN;
    const int lane = t & 63;
    const int w    = t >> 6;
    const int wm   = (w >> 1) * (BM / 2);
    const int wn   = (w & 1) * (BN / 2);
    const int lrow = lane & 15;
    const int q    = lane >> 4;
    const int sr16 = lane >> 2;
    const int sp   = lane & 3;

    auto stage = [&](int k0, int buf) {
        u16* As = SM + buf * TILE;
        u16* Bs = As + BM * 32;
        const u16* Abase = A0;
        int kloc = k0;
        if (K > 512) {
            int seg = k0 >> 9;
            Abase = (seg == 0) ? A0 : ((seg == 1) ? A1 : A2);
            kloc = k0 & 511;
        }
#pragma unroll
        for (int jj = 0; jj < AI / 4; ++jj) {
            int j = jj * 4 + w;
            int row = j * 16 + sr16;
            int c = (sp - (row >> 1)) & 3;
            gl_lds16(Abase + (size_t)(m0 + row) * 512 + kloc + c * 8, As + j * 512);
        }
#pragma unroll
        for (int jj = 0; jj < BI / 4; ++jj) {
            int j = jj * 4 + w;
            int row = j * 16 + sr16;
            int n = n0 + row;
            const u16* wr = (n < nsplit) ? (W0 + (size_t)n * K) : (W1 + (size_t)(n - nsplit) * K);
            int c = (sp - (row >> 1)) & 3;
            gl_lds16(wr + k0 + c * 8, Bs + j * 512);
        }
    };

    const f32x4 zero = {0.f, 0.f, 0.f, 0.f};
    f32x4 acc[MT][NT];
#pragma unroll
    for (int i = 0; i < MT; ++i)
#pragma unroll
        for (int j = 0; j < NT; ++j) acc[i][j] = zero;

    stage(0, 0);
    const int iters = K >> 5;
    int buf = 0;
    for (int it = 0; it < iters; ++it) {
        __syncthreads();
        if (it + 1 < iters) stage((it + 1) * 32, buf ^ 1);
        const u16* As = SM + buf * TILE;
        const u16* Bs = As + BM * 32;
        short8 af[MT], bfr[NT];
#pragma unroll
        for (int mt = 0; mt < MT; ++mt) {
            int row = wm + mt * 16 + lrow;
            int p = (q + (row >> 1)) & 3;
            af[mt] = *(const short8*)&As[row * 32 + p * 8];
        }
#pragma unroll
        for (int nt = 0; nt < NT; ++nt) {
            int row = wn + nt * 16 + lrow;
            int p = (q + (row >> 1)) & 3;
            bfr[nt] = *(const short8*)&Bs[row * 32 + p * 8];
        }
#pragma unroll
        for (int mt = 0; mt < MT; ++mt)
#pragma unroll
            for (int nt = 0; nt < NT; ++nt)
                acc[mt][nt] = __builtin_amdgcn_mfma_f32_16x16x32_bf16(af[mt], bfr[nt], acc[mt][nt], 0, 0, 0);
        buf ^= 1;
    }

#pragma unroll
    for (int mt = 0; mt < MT; ++mt) {
        int mb = m0 + wm + mt * 16 + q * 4;
#pragma unroll
        for (int nt = 0; nt < NT; ++nt) {
            int n = n0 + wn + nt * 16 + lrow;
            float bvv = (n < nsplit) ? bias0[n] : bias1[n - nsplit];
#pragma unroll
            for (int i = 0; i < 4; ++i) {
                float v = acc[mt][nt][i] + bvv;
                if (relu) v = fmaxf(v, 0.f);
                if (resbf) v += b2f(resbf[(size_t)(mb + i) * N + n]);
                if (out) out[(size_t)(mb + i) * N + n] = v;
                if (outbf) outbf[(size_t)(mb + i) * N + n] = f2b(v);
            }
        }
    }
}

// ---------------- fused decoder tail (per b)
__global__ __launch_bounds__(256) void k_dec(const float* __restrict__ x2T, const float* __restrict__ d2w,
                                             const float* __restrict__ d2b, const float* __restrict__ c1w,
                                             const float* __restrict__ c1b, const float* __restrict__ c2w,
                                             const float* __restrict__ c2b, float* __restrict__ out) {
    __shared__ float dv[64];
    __shared__ float d2s[256];
    const int b = blockIdx.x, t = threadIdx.x;
    const int lane = t & 63, w = t >> 6;
    if (t < 64) *(float4*)&d2s[t * 4] = *(const float4*)(d2w + t * 4);
    __syncthreads();
#pragma unroll 4
    for (int ci = 0; ci < 16; ++ci) {
        int c = w + ci * 4;
        const float* row = x2T + (size_t)(b * 64 + c) * 256;
        float acc = row[lane] * d2s[lane] + row[64 + lane] * d2s[64 + lane]
                  + row[128 + lane] * d2s[128 + lane] + row[192 + lane] * d2s[192 + lane];
        for (int off = 32; off; off >>= 1) acc += __shfl_xor(acc, off);
        if (lane == 0) dv[c] = acc + d2b[0];
    }
    __syncthreads();
    if (w == 0) {
        float part = 0.f;
        if (lane < 32) {
            float acc = c1b[lane];
            for (int c = 0; c < 64; ++c) acc += dv[c] * c1w[lane * 64 + c];
            part = fmaxf(acc, 0.f) * c2w[lane];
        }
        for (int off = 32; off; off >>= 1) part += __shfl_xor(part, off);
        if (lane == 0) out[b] = fabsf(part + c2b[0]);
    }
}

extern "C" void kernel_launch(void* const* d_in, const int* in_sizes, int n_in,
                              void* d_out, int out_size, void* d_ws, size_t ws_size,
                              hipStream_t stream) {
    const float* x     = (const float*)d_in[0];
    const float* occ   = (const float*)d_in[1];
    const float* projw = (const float*)d_in[2];
    const float* projb = (const float*)d_in[3];
    const float* ll1w  = (const float*)d_in[4];
    const float* ll1b  = (const float*)d_in[5];
    const float* ll2w  = (const float*)d_in[6];
    const float* ll2b  = (const float*)d_in[7];
    const float* g1w   = (const float*)d_in[8];
    const float* g1b   = (const float*)d_in[9];
    const float* g2w   = (const float*)d_in[10];
    const float* g2b   = (const float*)d_in[11];
    const float* gcw   = (const float*)d_in[12];
    const float* gcb   = (const float*)d_in[13];
    const float* taw   = (const float*)d_in[14];
    const float* tab   = (const float*)d_in[15];
    const float* d1w   = (const float*)d_in[16];
    const float* d1b   = (const float*)d_in[17];
    const float* d2w   = (const float*)d_in[18];
    const float* d2b   = (const float*)d_in[19];
    const float* c1w   = (const float*)d_in[20];
    const float* c1b   = (const float*)d_in[21];
    const float* c2w   = (const float*)d_in[22];
    const float* c2b   = (const float*)d_in[23];

    const size_t MR = (size_t)16384 * 512;
    float* ws   = (float*)d_ws;
    float* x2T  = ws;                          // d1 output (fp32), 16384*256
    float* vbuf = x2T + (size_t)16384 * 256;   // 16384*128 (ll output)
    float* proj = vbuf + (size_t)16384 * 128;
    u16* bfb     = (u16*)(proj + 16384);
    u16* xmA_bf  = bfb;
    u16* xmB_bf  = xmA_bf + MR;
    u16* x1_bf   = xmB_bf + MR;
    u16* x2_bf   = x1_bf + MR;
    u16* x1T_bf  = x2_bf + MR;                // ta output (bf16 only)
    u16* adpT_bf = x1T_bf + MR;               // 16384*64
    u16* Pb_bf   = adpT_bf + (size_t)16384 * 64;   // 16384*128 (P1|P2 bf16)
    u16* wb      = Pb_bf + (size_t)16384 * 128;    // contiguous bf16 weight arena
    u16* ll1w_bf = wb;                        // 98304
    u16* ll2w_bf = ll1w_bf + 98304;           // 98304
    u16* gcw_bf  = ll2w_bf + 98304;           // 2359296
    u16* taw_bf  = gcw_bf + 2359296;          // 262144
    u16* d1w_bf  = taw_bf + 262144;           // 131072

    k_cvt_all<<<2880, 256, 0, stream>>>(ll1w, ll2w, gcw, taw, d1w, wb);
    k_transpose<<<dim3(8, 256), 256, 0, stream>>>(x, xmA_bf);
    k_proj<<<256, 64, 0, stream>>>(occ, projw, projb, proj);

    u16* cur_bf = xmA_bf;
    u16* nxt_bf = xmB_bf;
    for (int l = 0; l < 3; ++l) {
        mfma_gemm<64, 64><<<dim3(256, 2), 256, 0, stream>>>(
            cur_bf, nullptr, nullptr,
            ll1w_bf + (size_t)l * 32768, ll2w_bf + (size_t)l * 32768, 64,
            ll1b + l * 64, ll2b + l * 64, nullptr, vbuf, nullptr, 128, 512, 0);
        k_pm<<<16384, 64, 0, stream>>>(cur_bf, vbuf, g1w + l * 576, g1b + l,
                                       g2w + l * 576, g2b + l, proj, Pb_bf);
        k_adp2<<<256, 256, 0, stream>>>(Pb_bf, adpT_bf);
        k_nconv2<<<dim3(4, 256), 256, 0, stream>>>(cur_bf, adpT_bf, x1_bf, x2_bf);
        mfma_gemm<128, 64><<<dim3(128, 8), 256, 0, stream>>>(
            cur_bf, x1_bf, x2_bf,
            gcw_bf + (size_t)l * 786432, gcw_bf + (size_t)l * 786432, 512,
            gcb + l * 512, gcb + l * 512, (l > 0 ? cur_bf : nullptr), nullptr, nxt_bf, 512, 1536, 1);
        { u16* tb = cur_bf; cur_bf = nxt_bf; nxt_bf = tb; }
    }
    // temporal_agg: bf16-only output
    mfma_gemm<128, 64><<<dim3(128, 8), 256, 0, stream>>>(
        cur_bf, nullptr, nullptr, taw_bf, taw_bf, 512, tab, tab, nullptr, nullptr, x1T_bf, 512, 512, 0);
    // decoder1: fp32 output for k_dec
    mfma_gemm<64, 64><<<dim3(256, 4), 256, 0, stream>>>(
        x1T_bf, nullptr, nullptr, d1w_bf, d1w_bf, 256, d1b, d1b, nullptr, x2T, nullptr, 256, 512, 1);
    k_dec<<<256, 256, 0, stream>>>(x2T, d2w, d2b, c1w, c1b, c2w, c2b, (float*)d_out);
}